// Round 5
// baseline (334.957 us; speedup 1.0000x reference)
//
#include <hip/hip_runtime.h>

// NeRF fused kernel for MI355X (gfx950) — round 5.
// Round 4 post-mortem: 47.4 us, MfmaUtil 31%, occupancy 17.7% (2 blocks/CU,
// LDS-capped at 76 KB by a_lds), bank conflicts 3.1M from the 136-stride.
// Fix: DELETE a_lds via a global h2-feature permutation baked into the setup
// tables: feature(slot) = 32*quad + mt*4 + r  (phase-2 D side)
//                       = 32*quad + ks*8 + j  (phase-3 B side)
// Both sides' per-lane slot sets partition identically by quad, so phase-2's
// packed output registers ARE phase-3's B-fragments (mt = 2ks + (j>>2),
// r = j&3) — zero LDS, zero shuffles for the h2 hand-off. LDS 76 KB -> 6 KB,
// __launch_bounds__(256,4) forces VGPR<=128 -> 4 blocks/CU = 16 waves/CU (2x
// TLP). W3 rows / b2 entries permuted to match in setup (b2 becomes natural
// order). Numerics otherwise identical to round 4 (absmax 16).

typedef _Float16 f16;
typedef __attribute__((ext_vector_type(2))) _Float16 h2v;
typedef __attribute__((ext_vector_type(8))) _Float16 half8;
typedef __attribute__((ext_vector_type(4))) float floatx4;

#define H 128
#define NS 64

static __device__ __forceinline__ h2v pkrtz(float a, float b) {
  return __builtin_bit_cast(h2v, __builtin_amdgcn_cvt_pkrtz(a, b));
}

// ---------------------------------------------------------------------------
// Setup: W2 -> A-frags for h2'^T = W2'^T @ h1^T with permuted h2 features:
//   frag (ks*8+mt), lane, elem j holds W2[k][n] with
//   k = ks*32 + (lane>>4)*8 + j   (h1 feature, unpermuted)
//   n = 32*(l16>>2) + mt*4 + (l16&3)   (permuted h2 slot -> real W2 column)
// W3 -> A-frags for f^T = W3'^T @ h2'^T, rows in matching permuted order:
//   frag ks, lane, elem j holds W3[32*(lane>>4) + ks*8 + j][l16] (pad l16>=4).
// b2 -> f16, natural order (permutation makes lane's bias pairs contiguous).
// ---------------------------------------------------------------------------
__global__ void nerf_setup(const float* __restrict__ W2, const float* __restrict__ W3,
                           const float* __restrict__ b2,
                           f16* __restrict__ wsW2, f16* __restrict__ wsW3,
                           f16* __restrict__ wsB2) {
  int t = blockIdx.x * blockDim.x + threadIdx.x;
  if (t < 8192) {                       // W2 frags
    int j2 = t & 3, lane = (t >> 2) & 63, mt = (t >> 8) & 7, ks = t >> 11;
    int l16 = lane & 15;
    int k = ks * 32 + ((lane >> 4) * 8) + 2 * j2;
    int n = 32 * (l16 >> 2) + mt * 4 + (l16 & 3);    // permuted column
    wsW2[2 * t]     = (f16)W2[k * H + n];
    wsW2[2 * t + 1] = (f16)W2[(k + 1) * H + n];
  } else if (t < 9216) {                // W3 frags (A-layout, permuted rows, padded)
    int u = t - 8192;
    int j2 = u & 3, lane = (u >> 2) & 63, ks = u >> 8;
    int c = lane & 15;
    int k3 = 32 * (lane >> 4) + ks * 8 + 2 * j2;     // permuted h2 feature
    wsW3[2 * u]     = (c < 4) ? (f16)W3[k3 * 4 + c]       : (f16)0.0f;
    wsW3[2 * u + 1] = (c < 4) ? (f16)W3[(k3 + 1) * 4 + c] : (f16)0.0f;
  } else if (t < 9344) {                // b2, natural order f16
    int i = t - 9216;
    wsB2[i] = (f16)b2[i];
  }
}

// ---------------------------------------------------------------------------
// Main: block = 4 rays = 4 waves; wave = 1 ray = 64 points; no barriers.
// ---------------------------------------------------------------------------
__global__ __launch_bounds__(256, 4) void nerf_main(
    const float* __restrict__ origins, const float* __restrict__ dirs,
    const float* __restrict__ W1, const float* __restrict__ b1,
    const float* __restrict__ b3,
    const f16* __restrict__ wsW2, const f16* __restrict__ wsW3,
    const f16* __restrict__ wsB2,
    float* __restrict__ out)
{
  __shared__ __align__(16) f16   popd[4][2][H];   // per-wave po/pd strips (2 KB)
  __shared__ __align__(16) float f_lds[4][64][4]; // render transpose (4 KB)

  const int t = threadIdx.x;
  const int w = t >> 6, lane = t & 63, quad = lane >> 4, l16 = lane & 15;
  const float delta = 4.0f / NS;       // near=2, far=6 baked
  const int ray = blockIdx.x * 4 + w;

  // ---- po/pd: po[k] = o@W1[:,k]+b1[k], pd[k] = d@W1[:,k]; f16 to LDS ----
  {
    const float o0 = origins[ray*3], o1 = origins[ray*3+1], o2 = origins[ray*3+2];
    const float d0 = dirs[ray*3],    d1 = dirs[ray*3+1],    d2 = dirs[ray*3+2];
    const int k0 = lane * 2;
    const float2 wr0 = *(const float2*)&W1[0*H + k0];
    const float2 wr1 = *(const float2*)&W1[1*H + k0];
    const float2 wr2 = *(const float2*)&W1[2*H + k0];
    const float2 bb  = *(const float2*)&b1[k0];
    float poa = fmaf(o2, wr2.x, fmaf(o1, wr1.x, fmaf(o0, wr0.x, bb.x)));
    float pob = fmaf(o2, wr2.y, fmaf(o1, wr1.y, fmaf(o0, wr0.y, bb.y)));
    float pda = fmaf(d2, wr2.x, fmaf(d1, wr1.x, d0 * wr0.x));
    float pdb = fmaf(d2, wr2.y, fmaf(d1, wr1.y, d0 * wr0.y));
    h2v po2; po2[0] = (f16)poa; po2[1] = (f16)pob;
    h2v pd2; pd2[0] = (f16)pda; pd2[1] = (f16)pdb;
    *(h2v*)&popd[w][0][k0] = po2;
    *(h2v*)&popd[w][1][k0] = pd2;
  }

  // m splats per n-tile: sample s = tr*16 + l16; m exact in f16 (mult of 1/32)
  half8 m8[4];
  #pragma unroll
  for (int tr = 0; tr < 4; ++tr)
    m8[tr] = (half8)(f16)(2.0f + (tr*16 + l16 + 0.5f) * delta);

  // ---- Phase 2: h2'^T = W2'^T @ h1^T, 4 ks x 4 tr x 8 mt MFMAs ----
  floatx4 acc[8][4];
  #pragma unroll
  for (int mt = 0; mt < 8; ++mt)
    #pragma unroll
    for (int tr = 0; tr < 4; ++tr) acc[mt][tr] = (floatx4)(0.0f);

  const half8* w2f = (const half8*)wsW2;
  const half8 z8 = (half8)(f16)0.0f;
  half8 awA[8], awB[8];
  #pragma unroll
  for (int mt = 0; mt < 8; ++mt) awA[mt] = w2f[mt*64 + lane];  // ks=0 prefetch

  #pragma unroll
  for (int ks = 0; ks < 4; ++ks) {
    half8* cur = (ks & 1) ? awB : awA;
    half8* nxt = (ks & 1) ? awA : awB;
    if (ks < 3) {
      #pragma unroll
      for (int mt = 0; mt < 8; ++mt) nxt[mt] = w2f[((ks+1)*8 + mt)*64 + lane];
    }
    const half8 po8 = *(const half8*)&popd[w][0][ks*32 + quad*8];
    const half8 pd8 = *(const half8*)&popd[w][1][ks*32 + quad*8];
    #pragma unroll
    for (int tr = 0; tr < 4; ++tr) {
      half8 hb = pd8 * m8[tr] + po8;                 // v_pk_fma_f16 x4
      hb = __builtin_elementwise_max(hb, z8);        // v_pk_max_f16 x4
      #pragma unroll
      for (int mt = 0; mt < 8; ++mt)
        acc[mt][tr] = __builtin_amdgcn_mfma_f32_16x16x32_f16(cur[mt], hb, acc[mt][tr], 0, 0, 0);
    }
  }

  // ---- Epilogue: bias+relu+pack IN REGISTERS. Lane's D slot (mt,r) = permuted
  // feature 32*quad + mt*4 + r of point tr*16+l16; bias pairs are contiguous. ----
  h2v hpk[8][4][2];
  {
    const uint2* bp = (const uint2*)wsB2;
    const h2v z2 = (h2v)(f16)0.0f;
    #pragma unroll
    for (int mt = 0; mt < 8; ++mt) {
      union { uint2 u; h2v h[2]; } bk;
      bk.u = bp[quad * 8 + mt];                      // b2[32q+4mt .. +3]
      #pragma unroll
      for (int tr = 0; tr < 4; ++tr) {
        h2v c0 = pkrtz(acc[mt][tr][0], acc[mt][tr][1]);
        h2v c1 = pkrtz(acc[mt][tr][2], acc[mt][tr][3]);
        hpk[mt][tr][0] = __builtin_elementwise_max((h2v)(c0 + bk.h[0]), z2);
        hpk[mt][tr][1] = __builtin_elementwise_max((h2v)(c1 + bk.h[1]), z2);
      }
    }
  }

  // ---- Phase 3: f^T = W3'^T @ h2'^T. B-frags ARE the hpk registers:
  // slot j=0..3 -> hpk[2ks][tr], j=4..7 -> hpk[2ks+1][tr]. ----
  const half8* w3f = (const half8*)wsW3;
  half8 w3[4];
  #pragma unroll
  for (int ks = 0; ks < 4; ++ks) w3[ks] = w3f[ks*64 + lane];
  floatx4 acc3[4];
  #pragma unroll
  for (int tr = 0; tr < 4; ++tr) acc3[tr] = (floatx4)(0.0f);
  #pragma unroll
  for (int tr = 0; tr < 4; ++tr)
    #pragma unroll
    for (int ks = 0; ks < 4; ++ks) {
      union { h2v h[4]; half8 v; } b;
      b.h[0] = hpk[2*ks][tr][0];   b.h[1] = hpk[2*ks][tr][1];
      b.h[2] = hpk[2*ks+1][tr][0]; b.h[3] = hpk[2*ks+1][tr][1];
      acc3[tr] = __builtin_amdgcn_mfma_f32_16x16x32_f16(w3[ks], b.v, acc3[tr], 0, 0, 0);
    }

  // D3: lane holds f[m = quad*4+r][point tr*16+l16]; quad 0 rows 0..3 are
  // (R,G,B,sigma). Transpose via tiny f_lds (same wave, no barrier).
  if (quad == 0) {
    #pragma unroll
    for (int tr = 0; tr < 4; ++tr) {
      float4 fv;
      fv.x = acc3[tr][0] + b3[0];
      fv.y = acc3[tr][1] + b3[1];
      fv.z = acc3[tr][2] + b3[2];
      fv.w = acc3[tr][3] + b3[3];
      *(float4*)&f_lds[w][tr*16 + l16][0] = fv;      // ds_write_b128
    }
  }

  // ---- Phase 4: volume rendering, wave renders its own ray, lane = sample ----
  {
    const float4 fv = *(const float4*)&f_lds[w][lane][0];
    const float sigma = fv.w;
    const float alpha = 1.0f - __expf(-sigma * delta);
    float S = sigma;
    #pragma unroll
    for (int off = 1; off < 64; off <<= 1) {
      float u = __shfl_up(S, off);
      if (lane >= off) S += u;
    }
    const float T  = __expf(-delta * (S - sigma));   // exclusive prefix
    const float wt = alpha * T;
    float cr = wt * fv.x, cg = wt * fv.y, cb = wt * fv.z;
    #pragma unroll
    for (int off = 32; off > 0; off >>= 1) {
      cr += __shfl_down(cr, off);
      cg += __shfl_down(cg, off);
      cb += __shfl_down(cb, off);
    }
    if (lane == 0) {
      out[ray*3+0] = cr; out[ray*3+1] = cg; out[ray*3+2] = cb;
    }
  }
}

extern "C" void kernel_launch(void* const* d_in, const int* in_sizes, int n_in,
                              void* d_out, int out_size, void* d_ws, size_t ws_size,
                              hipStream_t stream) {
  const float* origins = (const float*)d_in[0];
  const float* dirs    = (const float*)d_in[1];
  const float* W1      = (const float*)d_in[2];
  const float* b1      = (const float*)d_in[3];
  const float* W2      = (const float*)d_in[4];
  const float* b2      = (const float*)d_in[5];
  const float* W3      = (const float*)d_in[6];
  const float* b3      = (const float*)d_in[7];
  float* out = (float*)d_out;

  f16* wsW2 = (f16*)d_ws;          // 16384 f16 = 32 KB
  f16* wsW3 = wsW2 + 16384;        // 2048 f16  = 4 KB
  f16* wsB2 = wsW3 + 2048;         // 128 f16   = 256 B

  nerf_setup<<<37, 256, 0, stream>>>(W2, W3, b2, wsW2, wsW3, wsB2);
  nerf_main<<<16384 / 4, 256, 0, stream>>>(
      origins, dirs, W1, b1, b3, wsW2, wsW3, wsB2, out);
}

// Round 6
// 107.886 us; speedup vs baseline: 3.1047x; 3.1047x over previous
//
#include <hip/hip_runtime.h>

// NeRF fused kernel for MI355X (gfx950) — round 6.
// Round 5 post-mortem: __launch_bounds__(256,4) capped unified VGPR+AGPR at
// ~128 while live state needs ~230 -> accumulator spill to scratch (429 MB
// FETCH / 864 MB WRITE per dispatch, 264 us). The h2-permutation hand-off
// itself was CORRECT (absmax 16). Fix: restore (256,2) — the budget proven
// spill-free in round 4 — and keep the permutation:
//   h2 feature(slot) = 32*quad + mt*4 + r  (phase-2 D)  =  32*quad + ks*8 + j
//   (phase-3 B), so phase-2 output regs ARE phase-3 B-frags. Zero h2 LDS.
// Also: epilogue fused per-tr into phase 3 (shorter acc live ranges),
// B-frags built with vector inits (no unions).

typedef _Float16 f16;
typedef __attribute__((ext_vector_type(2))) _Float16 h2v;
typedef __attribute__((ext_vector_type(8))) _Float16 half8;
typedef __attribute__((ext_vector_type(4))) float floatx4;

#define H 128
#define NS 64

static __device__ __forceinline__ h2v pkrtz(float a, float b) {
  return __builtin_bit_cast(h2v, __builtin_amdgcn_cvt_pkrtz(a, b));
}

// ---------------------------------------------------------------------------
// Setup (identical to round 5, HW-verified): W2 -> A-frags with permuted h2
// columns n = 32*(l16>>2) + mt*4 + (l16&3); W3 -> A-frags with matching
// permuted rows k3 = 32*(lane>>4) + ks*8 + j (cols padded to 16); b2 natural.
// ---------------------------------------------------------------------------
__global__ void nerf_setup(const float* __restrict__ W2, const float* __restrict__ W3,
                           const float* __restrict__ b2,
                           f16* __restrict__ wsW2, f16* __restrict__ wsW3,
                           f16* __restrict__ wsB2) {
  int t = blockIdx.x * blockDim.x + threadIdx.x;
  if (t < 8192) {                       // W2 frags
    int j2 = t & 3, lane = (t >> 2) & 63, mt = (t >> 8) & 7, ks = t >> 11;
    int l16 = lane & 15;
    int k = ks * 32 + ((lane >> 4) * 8) + 2 * j2;
    int n = 32 * (l16 >> 2) + mt * 4 + (l16 & 3);    // permuted column
    wsW2[2 * t]     = (f16)W2[k * H + n];
    wsW2[2 * t + 1] = (f16)W2[(k + 1) * H + n];
  } else if (t < 9216) {                // W3 frags (A-layout, permuted rows, padded)
    int u = t - 8192;
    int j2 = u & 3, lane = (u >> 2) & 63, ks = u >> 8;
    int c = lane & 15;
    int k3 = 32 * (lane >> 4) + ks * 8 + 2 * j2;     // permuted h2 feature
    wsW3[2 * u]     = (c < 4) ? (f16)W3[k3 * 4 + c]       : (f16)0.0f;
    wsW3[2 * u + 1] = (c < 4) ? (f16)W3[(k3 + 1) * 4 + c] : (f16)0.0f;
  } else if (t < 9344) {                // b2, natural order f16
    int i = t - 9216;
    wsB2[i] = (f16)b2[i];
  }
}

// ---------------------------------------------------------------------------
// Main: block = 4 rays = 4 waves; wave = 1 ray = 64 points; no barriers.
// ---------------------------------------------------------------------------
__global__ __launch_bounds__(256, 2) void nerf_main(
    const float* __restrict__ origins, const float* __restrict__ dirs,
    const float* __restrict__ W1, const float* __restrict__ b1,
    const float* __restrict__ b3,
    const f16* __restrict__ wsW2, const f16* __restrict__ wsW3,
    const f16* __restrict__ wsB2,
    float* __restrict__ out)
{
  __shared__ __align__(16) f16   popd[4][2][H];   // per-wave po/pd strips (2 KB)
  __shared__ __align__(16) float f_lds[4][64][4]; // render transpose (4 KB)

  const int t = threadIdx.x;
  const int w = t >> 6, lane = t & 63, quad = lane >> 4, l16 = lane & 15;
  const float delta = 4.0f / NS;       // near=2, far=6 baked
  const int ray = blockIdx.x * 4 + w;

  // ---- po/pd: po[k] = o@W1[:,k]+b1[k], pd[k] = d@W1[:,k]; f16 to LDS ----
  {
    const float o0 = origins[ray*3], o1 = origins[ray*3+1], o2 = origins[ray*3+2];
    const float d0 = dirs[ray*3],    d1 = dirs[ray*3+1],    d2 = dirs[ray*3+2];
    const int k0 = lane * 2;
    const float2 wr0 = *(const float2*)&W1[0*H + k0];
    const float2 wr1 = *(const float2*)&W1[1*H + k0];
    const float2 wr2 = *(const float2*)&W1[2*H + k0];
    const float2 bb  = *(const float2*)&b1[k0];
    float poa = fmaf(o2, wr2.x, fmaf(o1, wr1.x, fmaf(o0, wr0.x, bb.x)));
    float pob = fmaf(o2, wr2.y, fmaf(o1, wr1.y, fmaf(o0, wr0.y, bb.y)));
    float pda = fmaf(d2, wr2.x, fmaf(d1, wr1.x, d0 * wr0.x));
    float pdb = fmaf(d2, wr2.y, fmaf(d1, wr1.y, d0 * wr0.y));
    h2v po2; po2[0] = (f16)poa; po2[1] = (f16)pob;
    h2v pd2; pd2[0] = (f16)pda; pd2[1] = (f16)pdb;
    *(h2v*)&popd[w][0][k0] = po2;
    *(h2v*)&popd[w][1][k0] = pd2;
  }

  // m splats per n-tile: sample s = tr*16 + l16; m exact in f16 (mult of 1/32)
  half8 m8[4];
  #pragma unroll
  for (int tr = 0; tr < 4; ++tr)
    m8[tr] = (half8)(f16)(2.0f + (tr*16 + l16 + 0.5f) * delta);

  // ---- Phase 2: h2'^T = W2'^T @ h1^T, 4 ks x 4 tr x 8 mt MFMAs ----
  floatx4 acc[8][4];
  #pragma unroll
  for (int mt = 0; mt < 8; ++mt)
    #pragma unroll
    for (int tr = 0; tr < 4; ++tr) acc[mt][tr] = (floatx4)(0.0f);

  const half8* w2f = (const half8*)wsW2;
  const half8 z8 = (half8)(f16)0.0f;
  half8 awA[8], awB[8];
  #pragma unroll
  for (int mt = 0; mt < 8; ++mt) awA[mt] = w2f[mt*64 + lane];  // ks=0 prefetch

  #pragma unroll
  for (int ks = 0; ks < 4; ++ks) {
    half8* cur = (ks & 1) ? awB : awA;
    half8* nxt = (ks & 1) ? awA : awB;
    if (ks < 3) {
      #pragma unroll
      for (int mt = 0; mt < 8; ++mt) nxt[mt] = w2f[((ks+1)*8 + mt)*64 + lane];
    }
    const half8 po8 = *(const half8*)&popd[w][0][ks*32 + quad*8];
    const half8 pd8 = *(const half8*)&popd[w][1][ks*32 + quad*8];
    #pragma unroll
    for (int tr = 0; tr < 4; ++tr) {
      half8 hb = pd8 * m8[tr] + po8;                 // v_pk_fma_f16 x4
      hb = __builtin_elementwise_max(hb, z8);        // v_pk_max_f16 x4
      #pragma unroll
      for (int mt = 0; mt < 8; ++mt)
        acc[mt][tr] = __builtin_amdgcn_mfma_f32_16x16x32_f16(cur[mt], hb, acc[mt][tr], 0, 0, 0);
    }
  }

  // ---- Phase 3 (fused epilogue): f^T = W3'^T @ h2'^T. For each tr, ks:
  // bias+relu+pack acc[2ks][tr], acc[2ks+1][tr] -> B-frag (features
  // 32*quad + 8ks + 0..7), MFMA against permuted-row W3 A-frags. ----
  h2v bk0[8], bk1[8];
  {
    const uint2* bp = (const uint2*)wsB2;
    #pragma unroll
    for (int mt = 0; mt < 8; ++mt) {
      uint2 u = bp[quad * 8 + mt];                   // b2[32q+4mt .. +3]
      bk0[mt] = __builtin_bit_cast(h2v, u.x);
      bk1[mt] = __builtin_bit_cast(h2v, u.y);
    }
  }
  const half8* w3f = (const half8*)wsW3;
  half8 w3[4];
  #pragma unroll
  for (int ks = 0; ks < 4; ++ks) w3[ks] = w3f[ks*64 + lane];

  const h2v z2 = (h2v)(f16)0.0f;
  floatx4 acc3[4];
  #pragma unroll
  for (int tr = 0; tr < 4; ++tr) {
    acc3[tr] = (floatx4)(0.0f);
    #pragma unroll
    for (int ks = 0; ks < 4; ++ks) {
      const int mt0 = 2*ks, mt1 = 2*ks + 1;
      h2v c0 = __builtin_elementwise_max((h2v)(pkrtz(acc[mt0][tr][0], acc[mt0][tr][1]) + bk0[mt0]), z2);
      h2v c1 = __builtin_elementwise_max((h2v)(pkrtz(acc[mt0][tr][2], acc[mt0][tr][3]) + bk1[mt0]), z2);
      h2v c2 = __builtin_elementwise_max((h2v)(pkrtz(acc[mt1][tr][0], acc[mt1][tr][1]) + bk0[mt1]), z2);
      h2v c3 = __builtin_elementwise_max((h2v)(pkrtz(acc[mt1][tr][2], acc[mt1][tr][3]) + bk1[mt1]), z2);
      half8 b = { c0[0], c0[1], c1[0], c1[1], c2[0], c2[1], c3[0], c3[1] };
      acc3[tr] = __builtin_amdgcn_mfma_f32_16x16x32_f16(w3[ks], b, acc3[tr], 0, 0, 0);
    }
  }

  // D3: lane holds f[m = quad*4+r][point tr*16+l16]; quad 0 rows 0..3 are
  // (R,G,B,sigma). Transpose via tiny f_lds (same wave, no barrier).
  if (quad == 0) {
    #pragma unroll
    for (int tr = 0; tr < 4; ++tr) {
      float4 fv;
      fv.x = acc3[tr][0] + b3[0];
      fv.y = acc3[tr][1] + b3[1];
      fv.z = acc3[tr][2] + b3[2];
      fv.w = acc3[tr][3] + b3[3];
      *(float4*)&f_lds[w][tr*16 + l16][0] = fv;      // ds_write_b128
    }
  }

  // ---- Phase 4: volume rendering, wave renders its own ray, lane = sample ----
  {
    const float4 fv = *(const float4*)&f_lds[w][lane][0];
    const float sigma = fv.w;
    const float alpha = 1.0f - __expf(-sigma * delta);
    float S = sigma;
    #pragma unroll
    for (int off = 1; off < 64; off <<= 1) {
      float u = __shfl_up(S, off);
      if (lane >= off) S += u;
    }
    const float T  = __expf(-delta * (S - sigma));   // exclusive prefix
    const float wt = alpha * T;
    float cr = wt * fv.x, cg = wt * fv.y, cb = wt * fv.z;
    #pragma unroll
    for (int off = 32; off > 0; off >>= 1) {
      cr += __shfl_down(cr, off);
      cg += __shfl_down(cg, off);
      cb += __shfl_down(cb, off);
    }
    if (lane == 0) {
      out[ray*3+0] = cr; out[ray*3+1] = cg; out[ray*3+2] = cb;
    }
  }
}

extern "C" void kernel_launch(void* const* d_in, const int* in_sizes, int n_in,
                              void* d_out, int out_size, void* d_ws, size_t ws_size,
                              hipStream_t stream) {
  const float* origins = (const float*)d_in[0];
  const float* dirs    = (const float*)d_in[1];
  const float* W1      = (const float*)d_in[2];
  const float* b1      = (const float*)d_in[3];
  const float* W2      = (const float*)d_in[4];
  const float* b2      = (const float*)d_in[5];
  const float* W3      = (const float*)d_in[6];
  const float* b3      = (const float*)d_in[7];
  float* out = (float*)d_out;

  f16* wsW2 = (f16*)d_ws;          // 16384 f16 = 32 KB
  f16* wsW3 = wsW2 + 16384;        // 2048 f16  = 4 KB
  f16* wsB2 = wsW3 + 2048;         // 128 f16   = 256 B

  nerf_setup<<<37, 256, 0, stream>>>(W2, W3, b2, wsW2, wsW3, wsB2);
  nerf_main<<<16384 / 4, 256, 0, stream>>>(
      origins, dirs, W1, b1, b3, wsW2, wsW3, wsB2, out);
}